// Round 5
// baseline (408.811 us; speedup 1.0000x reference)
//
#include <hip/hip_runtime.h>

typedef unsigned short u16;
typedef short bf16x8 __attribute__((ext_vector_type(8)));
typedef float f32x4 __attribute__((ext_vector_type(4)));

__device__ __forceinline__ u16 f2bf(float f) {
  union { float f; unsigned u; } c; c.f = f;
  unsigned r = (c.u + 0x7FFFu + ((c.u >> 16) & 1u)) >> 16;
  return (u16)r;
}
__device__ __forceinline__ float bf2f(u16 h) {
  union { unsigned u; float f; } c; c.u = ((unsigned)h) << 16;
  return c.f;
}
__device__ __forceinline__ void gload16(const void* g, void* l) {
  __builtin_amdgcn_global_load_lds(
      (const __attribute__((address_space(1))) unsigned*)g,
      (__attribute__((address_space(3))) unsigned*)l, 16, 0, 0);
}

// ---------------------------------------------------------------------------
// Weight prep: w_qkv [512,1536] -> wqkvT bf16 [1536,512]; w_out -> woutT [512,512]
// ---------------------------------------------------------------------------
__global__ __launch_bounds__(256) void prep_weights(
    const float* __restrict__ w_qkv, const float* __restrict__ w_out,
    u16* __restrict__ wqkvT, u16* __restrict__ woutT) {
  int i = blockIdx.x * 256 + threadIdx.x;
  const int T1 = 1536 * 512;
  if (i < T1) {
    int n = i >> 9, c = i & 511;
    wqkvT[i] = f2bf(w_qkv[(size_t)c * 1536 + n]);
  } else {
    int j = i - T1;
    int n = j >> 9, c = j & 511;
    woutT[j] = f2bf(w_out[(size_t)c * 512 + n]);
  }
}

// ---------------------------------------------------------------------------
// GroupNorm: x fp32 [32,1024,512] -> z bf16; 32 groups of 16 ch
// ---------------------------------------------------------------------------
__global__ __launch_bounds__(256) void groupnorm_k(
    const float* __restrict__ x, const float* __restrict__ scale,
    const float* __restrict__ bias, u16* __restrict__ z) {
  const int blk = blockIdx.x, b = blk >> 5, g = blk & 31;
  const float* xb = x + (size_t)b * 524288 + g * 16;
  u16* zb = z + (size_t)b * 524288 + g * 16;
  const int tid = threadIdx.x, lane = tid & 63, wid = tid >> 6;

  float4 vv[16];
  float s = 0.f, ss = 0.f;
#pragma unroll
  for (int i = 0; i < 16; ++i) {
    int e = (i * 256 + tid) * 4;
    int hw = e >> 4, j = e & 15;
    vv[i] = *(const float4*)&xb[(size_t)hw * 512 + j];
    s += vv[i].x + vv[i].y + vv[i].z + vv[i].w;
    ss += vv[i].x * vv[i].x + vv[i].y * vv[i].y + vv[i].z * vv[i].z + vv[i].w * vv[i].w;
  }
#pragma unroll
  for (int off = 32; off; off >>= 1) {
    s += __shfl_xor(s, off);
    ss += __shfl_xor(ss, off);
  }
  __shared__ float rs[4], rq[4];
  if (!lane) { rs[wid] = s; rq[wid] = ss; }
  __syncthreads();
  float S_ = rs[0] + rs[1] + rs[2] + rs[3];
  float Q_ = rq[0] + rq[1] + rq[2] + rq[3];
  const float inv_n = 1.f / 16384.f;
  float mean = S_ * inv_n;
  float var = Q_ * inv_n - mean * mean;
  float rstd = rsqrtf(var + 1e-5f);

  int j0 = (tid * 4) & 15;
  float sc0 = scale[g * 16 + j0 + 0] * rstd, sc1 = scale[g * 16 + j0 + 1] * rstd;
  float sc2 = scale[g * 16 + j0 + 2] * rstd, sc3 = scale[g * 16 + j0 + 3] * rstd;
  float bi0 = bias[g * 16 + j0 + 0] - mean * sc0, bi1 = bias[g * 16 + j0 + 1] - mean * sc1;
  float bi2 = bias[g * 16 + j0 + 2] - mean * sc2, bi3 = bias[g * 16 + j0 + 3] - mean * sc3;
#pragma unroll
  for (int i = 0; i < 16; ++i) {
    int e = (i * 256 + tid) * 4;
    int hw = e >> 4, j = e & 15;
    ushort4 o;
    o.x = f2bf(vv[i].x * sc0 + bi0);
    o.y = f2bf(vv[i].y * sc1 + bi1);
    o.z = f2bf(vv[i].z * sc2 + bi2);
    o.w = f2bf(vv[i].w * sc3 + bi3);
    *(ushort4*)&zb[(size_t)hw * 512 + j] = o;
  }
}

// ---------------------------------------------------------------------------
// Panel GEMM: C[M,N] = A[M,K] @ Bt[N,K]^T with B-panel resident in LDS.
// Block: stages Bt panel [128 n-rows][512 k] = 128 KB into LDS ONCE
// (granule-swizzled), then a BARRIER-FREE K-loop: per 32-K chunk each wave
// loads A-frags straight from global to VGPRs (2x b128), 4 swizzled
// ds_read_b128 for B, 8 independent MFMA. 8 waves (4M x 2N), per-wave 32x64.
// 2 M-tiles (256 rows) per block amortize the panel stage.
// SEG=2 (K=1024) re-stages the panel per 512-K segment (only barriers used).
// EPI 0: q,k rowmajor (+bias, q scaled), v -> TRANSPOSED [b][c][p]
// EPI 1: bf16 store   EPI 2: fp32 +bias+resid
// ---------------------------------------------------------------------------
#define QSCALE 0.04419417382415922f

template <int EPI, int SEG>
__global__ __launch_bounds__(512, 2) void gemm_panel(
    const u16* __restrict__ A, const u16* __restrict__ Bt,
    int nPan, int gxy, int N,
    long long sAb, long long sBb, long long sCb,
    const float* __restrict__ bias, const float* __restrict__ resid,
    u16* __restrict__ qb, u16* __restrict__ kb, u16* __restrict__ vtb,
    u16* __restrict__ outb, float* __restrict__ outf) {
  const int Ktot = SEG * 512;
  // XCD-chunked bijective remap (all grids are multiples of 8)
  int nb = gridDim.x, orig = blockIdx.x, id = orig;
  if (!(nb & 7)) { int chunk = nb >> 3; id = (orig & 7) * chunk + (orig >> 3); }
  int z = id / gxy; int rem = id - z * gxy;
  int pan = rem % nPan; int mb = rem / nPan;

  const u16* Ab = A + (size_t)z * sAb;
  const u16* Bb = Bt + (size_t)z * sBb;

  __shared__ u16 Bs[128 * 512];  // 128 KB: one K-segment of the panel

  const int tid = threadIdx.x;
  const int lane = tid & 63, wid = tid >> 6;
  const int wm = wid >> 1;          // 0..3  (M quarter within 128-row m-tile)
  const int wn = wid & 1;           // 0..1  (N half of the 128-col panel)
  const int l15 = lane & 15, l4 = lane >> 4;
  const int n0 = pan * 128;
  const int m0 = mb * 256;

  f32x4 acc[2][2][4];               // [mtile][mi][ni]
#pragma unroll
  for (int m = 0; m < 2; ++m)
#pragma unroll
    for (int i = 0; i < 2; ++i)
#pragma unroll
      for (int j = 0; j < 4; ++j)
#pragma unroll
        for (int r = 0; r < 4; ++r) acc[m][i][j][r] = 0.f;

  const int srow8 = tid >> 6;       // 0..7 row-within-round
  const int gi0 = tid & 63;         // granule within 512-K row

#pragma unroll
  for (int seg = 0; seg < SEG; ++seg) {
    if (seg) __syncthreads();       // all waves done reading previous segment
    // stage one segment of the panel: 16 rounds x 8 rows
#pragma unroll
    for (int j = 0; j < 16; ++j) {
      const int row = j * 8 + srow8;
      const int gis = (gi0 & 56) | ((gi0 & 7) ^ (row & 7));  // pre-swizzled src
      gload16(Bb + (size_t)(n0 + row) * Ktot + seg * 512 + gis * 8,
              &Bs[j * 4096 + tid * 8]);
    }
    __syncthreads();                // drains vmcnt; panel ready (read-only now)

#pragma unroll
    for (int m = 0; m < 2; ++m) {
      const u16* Arow = Ab + (size_t)(m0 + m * 128 + wm * 32) * Ktot + seg * 512;
#pragma unroll 4
      for (int kc = 0; kc < 16; ++kc) {
        bf16x8 af[2], bq[4];
#pragma unroll
        for (int i = 0; i < 2; ++i)
          af[i] = *(const bf16x8*)&Arow[(size_t)(i * 16 + l15) * Ktot + kc * 32 + l4 * 8];
#pragma unroll
        for (int ni = 0; ni < 4; ++ni) {
          const int rr = wn * 64 + ni * 16 + l15;
          const int gi = kc * 4 + l4;
          const int gis = (gi & 56) | ((gi & 7) ^ (rr & 7));
          bq[ni] = *(const bf16x8*)&Bs[rr * 512 + gis * 8];
        }
#pragma unroll
        for (int i = 0; i < 2; ++i)
#pragma unroll
          for (int ni = 0; ni < 4; ++ni)
            acc[m][i][ni] = __builtin_amdgcn_mfma_f32_16x16x32_bf16(
                af[i], bq[ni], acc[m][i][ni], 0, 0, 0);
      }
    }
  }

  // epilogue (2 m-tiles)
#pragma unroll
  for (int m = 0; m < 2; ++m) {
#pragma unroll
    for (int mi = 0; mi < 2; ++mi) {
#pragma unroll
      for (int ni = 0; ni < 4; ++ni) {
        const int gr0 = m0 + m * 128 + wm * 32 + mi * 16 + l4 * 4;
        const int gc = n0 + wn * 64 + ni * 16 + l15;
        if (EPI == 0) {
          const int bsel = gc >> 9, cin = gc & 511;
          const float bs = bias[gc];
          if (bsel < 2) {
            u16* dst = bsel ? kb : qb;
#pragma unroll
            for (int r = 0; r < 4; ++r) {
              float vvv = acc[m][mi][ni][r] + bs;
              if (bsel == 0) vvv *= QSCALE;
              dst[(size_t)(gr0 + r) * 512 + cin] = f2bf(vvv);
            }
          } else {
            ushort4 o;
            o.x = f2bf(acc[m][mi][ni][0] + bs);
            o.y = f2bf(acc[m][mi][ni][1] + bs);
            o.z = f2bf(acc[m][mi][ni][2] + bs);
            o.w = f2bf(acc[m][mi][ni][3] + bs);
            const int bb = gr0 >> 10, p = gr0 & 1023;
            *(ushort4*)&vtb[(size_t)bb * 524288 + (size_t)cin * 1024 + p] = o;
          }
        } else if (EPI == 1) {
#pragma unroll
          for (int r = 0; r < 4; ++r)
            outb[(size_t)z * sCb + (size_t)(gr0 + r) * N + gc] =
                f2bf(acc[m][mi][ni][r]);
        } else {
#pragma unroll
          for (int r = 0; r < 4; ++r)
            outf[(size_t)(gr0 + r) * N + gc] =
                acc[m][mi][ni][r] + bias[gc] + resid[(size_t)(gr0 + r) * N + gc];
        }
      }
    }
  }
}

// ---------------------------------------------------------------------------
// Row softmax over S bf16 [32768 rows][1024], in place, fp32 math
// ---------------------------------------------------------------------------
__global__ __launch_bounds__(256) void softmax_rows(u16* __restrict__ S) {
  const size_t row = blockIdx.x;
  u16* p = S + row * 1024;
  const int tid = threadIdx.x, lane = tid & 63, wid = tid >> 6;
  ushort4 raw = ((const ushort4*)p)[tid];
  float v0 = bf2f(raw.x), v1 = bf2f(raw.y), v2 = bf2f(raw.z), v3 = bf2f(raw.w);
  float mx = fmaxf(fmaxf(v0, v1), fmaxf(v2, v3));
#pragma unroll
  for (int off = 32; off; off >>= 1) mx = fmaxf(mx, __shfl_xor(mx, off));
  __shared__ float red[8];
  if (!lane) red[wid] = mx;
  __syncthreads();
  mx = fmaxf(fmaxf(red[0], red[1]), fmaxf(red[2], red[3]));
  float e0 = __expf(v0 - mx), e1 = __expf(v1 - mx), e2 = __expf(v2 - mx), e3 = __expf(v3 - mx);
  float s = e0 + e1 + e2 + e3;
#pragma unroll
  for (int off = 32; off; off >>= 1) s += __shfl_xor(s, off);
  if (!lane) red[4 + wid] = s;
  __syncthreads();
  float inv = 1.0f / (red[4] + red[5] + red[6] + red[7]);
  ushort4 o;
  o.x = f2bf(e0 * inv); o.y = f2bf(e1 * inv); o.z = f2bf(e2 * inv); o.w = f2bf(e3 * inv);
  ((ushort4*)p)[tid] = o;
}

// ---------------------------------------------------------------------------
extern "C" void kernel_launch(void* const* d_in, const int* in_sizes, int n_in,
                              void* d_out, int out_size, void* d_ws, size_t ws_size,
                              hipStream_t stream) {
  const float* x = (const float*)d_in[0];
  const float* gn_scale = (const float*)d_in[2];
  const float* gn_bias = (const float*)d_in[3];
  const float* w_qkv = (const float*)d_in[4];
  const float* b_qkv = (const float*)d_in[5];
  const float* w_out = (const float*)d_in[6];
  const float* b_out = (const float*)d_in[7];
  float* out = (float*)d_out;

  char* ws = (char*)d_ws;
  const size_t MB = 1024ull * 1024ull;
  u16* qb = (u16*)(ws + 0 * MB);      // 32 MB  [32768][512]
  u16* kb = (u16*)(ws + 32 * MB);     // 32 MB  [32768][512]
  u16* vt = (u16*)(ws + 64 * MB);     // 32 MB  [32][512][1024]  (V transposed)
  u16* zO = (u16*)(ws + 128 * MB);    // 32 MB  z, later reused as O
  u16* S = (u16*)(ws + 160 * MB);     // 64 MB  [32][1024][1024]
  u16* wqkvT = (u16*)(ws + 224 * MB); // 1.5 MB [1536][512]
  u16* woutT = (u16*)(ws + 226 * MB); // 0.5 MB [512][512]

  prep_weights<<<4096, 256, 0, stream>>>(w_qkv, w_out, wqkvT, woutT);
  groupnorm_k<<<1024, 256, 0, stream>>>(x, gn_scale, gn_bias, zO);

  // QKV: z[32768,512] @ wqkvT^T -> q,k (rowmajor), v (transposed)
  // nPan=12, mb=128 -> grid 1536
  gemm_panel<0, 1><<<1536, 512, 0, stream>>>(
      zO, wqkvT, 12, 1536, 1536, 0, 0, 0, b_qkv, nullptr,
      qb, kb, vt, nullptr, nullptr);

  // S = q @ k^T (batched over 32): nPan=8, mb=4 -> gxy=32, grid 1024
  gemm_panel<1, 1><<<1024, 512, 0, stream>>>(
      qb, kb, 8, 32, 1024, 1024 * 512, 1024 * 512, 1024 * 1024,
      nullptr, nullptr, nullptr, nullptr, nullptr, S, nullptr);

  softmax_rows<<<32768, 256, 0, stream>>>(S);

  // O = P @ V (vt [512][1024] per batch): K=1024 (SEG=2), nPan=4, mb=4 -> gxy=16, grid 512
  gemm_panel<1, 2><<<512, 512, 0, stream>>>(
      S, vt, 4, 16, 512, 1024 * 1024, 512 * 1024, 1024 * 512,
      nullptr, nullptr, nullptr, nullptr, nullptr, zO, nullptr);

  // out = O @ w_out^T + b_out + x: nPan=4, mb=128 -> gxy=512, grid 512
  gemm_panel<2, 1><<<512, 512, 0, stream>>>(
      zO, woutT, 4, 512, 512, 0, 0, 0, b_out, x,
      nullptr, nullptr, nullptr, nullptr, out);
}

// Round 7
// 270.688 us; speedup vs baseline: 1.5103x; 1.5103x over previous
//
#include <hip/hip_runtime.h>

typedef unsigned short u16;
typedef short bf16x8 __attribute__((ext_vector_type(8)));
typedef float f32x4 __attribute__((ext_vector_type(4)));

__device__ __forceinline__ u16 f2bf(float f) {
  union { float f; unsigned u; } c; c.f = f;
  unsigned r = (c.u + 0x7FFFu + ((c.u >> 16) & 1u)) >> 16;
  return (u16)r;
}
__device__ __forceinline__ float bf2f(u16 h) {
  union { unsigned u; float f; } c; c.u = ((unsigned)h) << 16;
  return c.f;
}
__device__ __forceinline__ void gload16(const void* g, void* l) {
  __builtin_amdgcn_global_load_lds(
      (const __attribute__((address_space(1))) unsigned*)g,
      (__attribute__((address_space(3))) unsigned*)l, 16, 0, 0);
}

// ---------------------------------------------------------------------------
// Weight prep: w_qkv [512,1536] -> wqkvT bf16 [1536,512]; w_out -> woutT [512,512]
// ---------------------------------------------------------------------------
__global__ __launch_bounds__(256) void prep_weights(
    const float* __restrict__ w_qkv, const float* __restrict__ w_out,
    u16* __restrict__ wqkvT, u16* __restrict__ woutT) {
  int i = blockIdx.x * 256 + threadIdx.x;
  const int T1 = 1536 * 512;
  if (i < T1) {
    int n = i >> 9, c = i & 511;
    wqkvT[i] = f2bf(w_qkv[(size_t)c * 1536 + n]);
  } else {
    int j = i - T1;
    int n = j >> 9, c = j & 511;
    woutT[j] = f2bf(w_out[(size_t)c * 512 + n]);
  }
}

// ---------------------------------------------------------------------------
// GroupNorm: x fp32 [32,1024,512] -> z bf16; 32 groups of 16 ch
// ---------------------------------------------------------------------------
__global__ __launch_bounds__(256) void groupnorm_k(
    const float* __restrict__ x, const float* __restrict__ scale,
    const float* __restrict__ bias, u16* __restrict__ z) {
  const int blk = blockIdx.x, b = blk >> 5, g = blk & 31;
  const float* xb = x + (size_t)b * 524288 + g * 16;
  u16* zb = z + (size_t)b * 524288 + g * 16;
  const int tid = threadIdx.x, lane = tid & 63, wid = tid >> 6;

  float4 vv[16];
  float s = 0.f, ss = 0.f;
#pragma unroll
  for (int i = 0; i < 16; ++i) {
    int e = (i * 256 + tid) * 4;
    int hw = e >> 4, j = e & 15;
    vv[i] = *(const float4*)&xb[(size_t)hw * 512 + j];
    s += vv[i].x + vv[i].y + vv[i].z + vv[i].w;
    ss += vv[i].x * vv[i].x + vv[i].y * vv[i].y + vv[i].z * vv[i].z + vv[i].w * vv[i].w;
  }
#pragma unroll
  for (int off = 32; off; off >>= 1) {
    s += __shfl_xor(s, off);
    ss += __shfl_xor(ss, off);
  }
  __shared__ float rs[4], rq[4];
  if (!lane) { rs[wid] = s; rq[wid] = ss; }
  __syncthreads();
  float S_ = rs[0] + rs[1] + rs[2] + rs[3];
  float Q_ = rq[0] + rq[1] + rq[2] + rq[3];
  const float inv_n = 1.f / 16384.f;
  float mean = S_ * inv_n;
  float var = Q_ * inv_n - mean * mean;
  float rstd = rsqrtf(var + 1e-5f);

  int j0 = (tid * 4) & 15;
  float sc0 = scale[g * 16 + j0 + 0] * rstd, sc1 = scale[g * 16 + j0 + 1] * rstd;
  float sc2 = scale[g * 16 + j0 + 2] * rstd, sc3 = scale[g * 16 + j0 + 3] * rstd;
  float bi0 = bias[g * 16 + j0 + 0] - mean * sc0, bi1 = bias[g * 16 + j0 + 1] - mean * sc1;
  float bi2 = bias[g * 16 + j0 + 2] - mean * sc2, bi3 = bias[g * 16 + j0 + 3] - mean * sc3;
#pragma unroll
  for (int i = 0; i < 16; ++i) {
    int e = (i * 256 + tid) * 4;
    int hw = e >> 4, j = e & 15;
    ushort4 o;
    o.x = f2bf(vv[i].x * sc0 + bi0);
    o.y = f2bf(vv[i].y * sc1 + bi1);
    o.z = f2bf(vv[i].z * sc2 + bi2);
    o.w = f2bf(vv[i].w * sc3 + bi3);
    *(ushort4*)&zb[(size_t)hw * 512 + j] = o;
  }
}

// ---------------------------------------------------------------------------
// 8-phase 256x256xBK64 GEMM (round-3 structure) + XCD-locality scheduling.
// EPI 0: q,k rowmajor (+bias, q scaled), v -> TRANSPOSED [b][c][p]
// EPI 2: fp32 +bias+resid
// EPI 3: P' = exp(S) bf16 + partial row-sums lsum[z][row][bx*4+wn] (16/row)
// EPI 4: bf16 store of acc / (sum of 16 lsum partials)
// ---------------------------------------------------------------------------
#define QSCALE 0.04419417382415922f

template <int EPI>
__global__ __launch_bounds__(512, 2) void gemm8p(
    const u16* __restrict__ A, const u16* __restrict__ Bt,
    int gx, int gxy, int N, int K,
    int sched, int sp1, int sp2,
    long long sAb, long long sBb, long long sCb,
    const float* __restrict__ bias, const float* __restrict__ resid,
    u16* __restrict__ qb, u16* __restrict__ kb, u16* __restrict__ vt,
    u16* __restrict__ outb, float* __restrict__ outf,
    float* __restrict__ lsum) {
  // XCD-locality remap: consecutive blockIdx round-robin across 8 XCDs.
  const int orig = blockIdx.x;
  const int xcd = orig & 7, jj = orig >> 3;
  int id;
  if (sched == 0) {           // row-mode: panels fastest within an M-slab
    int pan = jj % gx, loc = jj / gx;
    id = (xcd * sp1 + loc) * gx + pan;
  } else {                    // batch-mode: batches pinned to XCDs
    int tile = jj % gxy, bl = jj / gxy;
    id = (xcd * sp2 + bl) * gxy + tile;
  }
  const int z = id / gxy;
  const int r2 = id - z * gxy;
  const int by = r2 / gx, bx = r2 - by * gx;

  const u16* Ab = A + (size_t)z * sAb;
  const u16* Bb = Bt + (size_t)z * sBb;

  __shared__ u16 As[2][2][8192];  // [buf][half][128*64]
  __shared__ u16 Bs[2][2][8192];

  const int tid = threadIdx.x;
  const int lane = tid & 63, wid = tid >> 6;
  const int wm = wid & 1, wn = wid >> 1;
  const int l15 = lane & 15, l4 = lane >> 4;
  const int m0 = by * 256, n0 = bx * 256;

  // staging ownership: wid 0,1 -> A h0; 2,3 -> A h1; 4,5 -> B h0; 6,7 -> B h1
  const int own_is_b = wid >> 2;
  const int own_h = (wid >> 1) & 1;
  const int prow = ((wid & 1) << 6) | lane;        // 0..127 within pair
  const int srow = prow >> 3;
  const int scol = ((prow & 7) ^ (srow & 7)) << 3; // pre-swizzled src col
  const u16* own_base = (own_is_b ? Bb : Ab) +
      (size_t)((own_is_b ? n0 : m0) + own_h * 128 + srow) * K + scol;
  const int ldsbase = ((wid & 1) << 6) * 8;        // ushort offset, wave-uniform

  f32x4 acc[8][4];
#pragma unroll
  for (int i = 0; i < 8; ++i)
#pragma unroll
    for (int j = 0; j < 4; ++j)
#pragma unroll
      for (int r = 0; r < 4; ++r) acc[i][j][r] = 0.f;

  const int NT = K >> 6;

  auto stage = [&](int k0, int buf) {
    u16* l0 = (own_is_b ? &Bs[buf][own_h][0] : &As[buf][own_h][0]) + ldsbase;
    const u16* g0 = own_base + k0;
#pragma unroll
    for (int j = 0; j < 8; ++j)
      gload16(g0 + (size_t)(j * 16) * K, l0 + j * 1024);
  };

  // prologue: tile 0 into buf 0
  stage(0, 0);
  asm volatile("s_waitcnt vmcnt(0)" ::: "memory");
  __builtin_amdgcn_s_barrier();

  for (int t = 0; t < NT; ++t) {
    const int cur = t & 1;
    const bool pre = (t + 1 < NT);
    const u16* Ah = &As[cur][wm][0];
    const u16* Bh = &Bs[cur][wn >> 1][0];
    const int rbB = (wn & 1) << 6;
    bf16x8 bq[4][2];
#pragma unroll
    for (int q = 0; q < 4; ++q) {
      bf16x8 af[2][2];
      if (q == 0) {
#pragma unroll
        for (int i = 0; i < 4; ++i) {
          const int rr = rbB + i * 16 + l15;
          const int sw = rr & 7;
          bq[i][0] = *(const bf16x8*)&Bh[rr * 64 + ((l4 ^ sw) << 3)];
          bq[i][1] = *(const bf16x8*)&Bh[rr * 64 + (((4 + l4) ^ sw) << 3)];
        }
      }
#pragma unroll
      for (int j = 0; j < 2; ++j) {
        const int rr = (q * 2 + j) * 16 + l15;
        const int sw = rr & 7;
        af[j][0] = *(const bf16x8*)&Ah[rr * 64 + ((l4 ^ sw) << 3)];
        af[j][1] = *(const bf16x8*)&Ah[rr * 64 + (((4 + l4) ^ sw) << 3)];
      }
      if (q == 0 && pre) stage((t + 1) << 6, cur ^ 1);
      __builtin_amdgcn_s_barrier();
      asm volatile("s_waitcnt lgkmcnt(0)" ::: "memory");
      __builtin_amdgcn_sched_barrier(0);
      __builtin_amdgcn_s_setprio(1);
#pragma unroll
      for (int j = 0; j < 2; ++j)
#pragma unroll
        for (int ni = 0; ni < 4; ++ni) {
          acc[q * 2 + j][ni] = __builtin_amdgcn_mfma_f32_16x16x32_bf16(
              af[j][0], bq[ni][0], acc[q * 2 + j][ni], 0, 0, 0);
          acc[q * 2 + j][ni] = __builtin_amdgcn_mfma_f32_16x16x32_bf16(
              af[j][1], bq[ni][1], acc[q * 2 + j][ni], 0, 0, 0);
        }
      __builtin_amdgcn_s_setprio(0);
      if (q == 3 && pre) asm volatile("s_waitcnt vmcnt(0)" ::: "memory");
      __builtin_amdgcn_s_barrier();
    }
  }

  // ---------------- epilogues ----------------
  if (EPI == 0) {
#pragma unroll
    for (int mi = 0; mi < 8; ++mi) {
#pragma unroll
      for (int ni = 0; ni < 4; ++ni) {
        const int gr0 = m0 + wm * 128 + mi * 16 + l4 * 4;
        const int gc = n0 + wn * 64 + ni * 16 + l15;
        const int bsel = gc >> 9, cin = gc & 511;
        const float bs = bias[gc];
        if (bsel < 2) {
          u16* dst = bsel ? kb : qb;
#pragma unroll
          for (int r = 0; r < 4; ++r) {
            float vvv = acc[mi][ni][r] + bs;
            if (bsel == 0) vvv *= QSCALE;
            dst[(size_t)(gr0 + r) * 512 + cin] = f2bf(vvv);
          }
        } else {
          ushort4 o;
          o.x = f2bf(acc[mi][ni][0] + bs);
          o.y = f2bf(acc[mi][ni][1] + bs);
          o.z = f2bf(acc[mi][ni][2] + bs);
          o.w = f2bf(acc[mi][ni][3] + bs);
          const int bb = gr0 >> 10, p = gr0 & 1023;
          *(ushort4*)&vt[(size_t)bb * 524288 + (size_t)cin * 1024 + p] = o;
        }
      }
    }
  } else if (EPI == 2) {
#pragma unroll
    for (int mi = 0; mi < 8; ++mi) {
#pragma unroll
      for (int ni = 0; ni < 4; ++ni) {
        const int gr0 = m0 + wm * 128 + mi * 16 + l4 * 4;
        const int gc = n0 + wn * 64 + ni * 16 + l15;
#pragma unroll
        for (int r = 0; r < 4; ++r)
          outf[(size_t)(gr0 + r) * N + gc] =
              acc[mi][ni][r] + bias[gc] + resid[(size_t)(gr0 + r) * N + gc];
      }
    }
  } else if (EPI == 3) {
    // P' = exp(S); partial row sums: 16 partials/row, slot = bx*4+wn
    float rs_[8][4];
#pragma unroll
    for (int mi = 0; mi < 8; ++mi)
#pragma unroll
      for (int r = 0; r < 4; ++r) rs_[mi][r] = 0.f;
#pragma unroll
    for (int mi = 0; mi < 8; ++mi) {
      const int gr0 = m0 + wm * 128 + mi * 16 + l4 * 4;
#pragma unroll
      for (int ni = 0; ni < 4; ++ni) {
        const int gc = n0 + wn * 64 + ni * 16 + l15;
#pragma unroll
        for (int r = 0; r < 4; ++r) {
          float e = __expf(acc[mi][ni][r]);
          rs_[mi][r] += e;
          outb[(size_t)z * sCb + (size_t)(gr0 + r) * N + gc] = f2bf(e);
        }
      }
    }
#pragma unroll
    for (int mi = 0; mi < 8; ++mi) {
      const int gr0 = m0 + wm * 128 + mi * 16 + l4 * 4;
#pragma unroll
      for (int r = 0; r < 4; ++r) {
        float v = rs_[mi][r];
        v += __shfl_xor(v, 1);
        v += __shfl_xor(v, 2);
        v += __shfl_xor(v, 4);
        v += __shfl_xor(v, 8);
        if (l15 == 0)
          lsum[((size_t)z * 1024 + gr0 + r) * 16 + bx * 4 + wn] = v;
      }
    }
  } else {  // EPI == 4: PV output scaled by 1/rowsum (16 partials)
#pragma unroll
    for (int mi = 0; mi < 8; ++mi) {
      const int gr0 = m0 + wm * 128 + mi * 16 + l4 * 4;
      float inv[4];
#pragma unroll
      for (int r = 0; r < 4; ++r) {
        const float* lp = &lsum[((size_t)z * 1024 + gr0 + r) * 16];
        const float4 a0 = *(const float4*)&lp[0];
        const float4 a1 = *(const float4*)&lp[4];
        const float4 a2 = *(const float4*)&lp[8];
        const float4 a3 = *(const float4*)&lp[12];
        inv[r] = 1.0f / (a0.x + a0.y + a0.z + a0.w + a1.x + a1.y + a1.z + a1.w +
                         a2.x + a2.y + a2.z + a2.w + a3.x + a3.y + a3.z + a3.w);
      }
#pragma unroll
      for (int ni = 0; ni < 4; ++ni) {
        const int gc = n0 + wn * 64 + ni * 16 + l15;
#pragma unroll
        for (int r = 0; r < 4; ++r)
          outb[(size_t)z * sCb + (size_t)(gr0 + r) * N + gc] =
              f2bf(acc[mi][ni][r] * inv[r]);
      }
    }
  }
}

// ---------------------------------------------------------------------------
extern "C" void kernel_launch(void* const* d_in, const int* in_sizes, int n_in,
                              void* d_out, int out_size, void* d_ws, size_t ws_size,
                              hipStream_t stream) {
  const float* x = (const float*)d_in[0];
  const float* gn_scale = (const float*)d_in[2];
  const float* gn_bias = (const float*)d_in[3];
  const float* w_qkv = (const float*)d_in[4];
  const float* b_qkv = (const float*)d_in[5];
  const float* w_out = (const float*)d_in[6];
  const float* b_out = (const float*)d_in[7];
  float* out = (float*)d_out;

  char* ws = (char*)d_ws;
  const size_t MB = 1024ull * 1024ull;
  u16* qb = (u16*)(ws + 0 * MB);      // 32 MB  [32768][512]
  u16* kb = (u16*)(ws + 32 * MB);     // 32 MB  [32768][512]
  u16* vt = (u16*)(ws + 64 * MB);     // 32 MB  [32][512][1024]  (V transposed)
  float* lsum = (float*)(ws + 96 * MB); // 2 MB [32][1024][16] partial row sums
  u16* zO = (u16*)(ws + 128 * MB);    // 32 MB  z, later reused as O
  u16* S = (u16*)(ws + 160 * MB);     // 64 MB  [32][1024][1024] (P' = exp(S))
  u16* wqkvT = (u16*)(ws + 224 * MB); // 1.5 MB [1536][512]
  u16* woutT = (u16*)(ws + 226 * MB); // 0.5 MB [512][512]

  prep_weights<<<4096, 256, 0, stream>>>(w_qkv, w_out, wqkvT, woutT);
  groupnorm_k<<<1024, 256, 0, stream>>>(x, gn_scale, gn_bias, zO);

  // QKV: z @ wqkvT^T -> q,k (rowmajor, q scaled), v (transposed)
  // row-mode: XCD slab of 16 m-blocks, 6 panels cycle fastest
  gemm8p<0><<<768, 512, 0, stream>>>(
      zO, wqkvT, 6, 768, 1536, 512, 0, 16, 0, 0, 0, 0, b_qkv, nullptr,
      qb, kb, vt, nullptr, nullptr, nullptr);

  // P' = exp(q @ k^T) (batched over 32) + partial row sums
  // batch-mode: 4 batches per XCD, 16 tiles each
  gemm8p<3><<<512, 512, 0, stream>>>(
      qb, kb, 4, 16, 1024, 512, 1, 0, 4, 1024 * 512, 1024 * 512, 1024 * 1024,
      nullptr, nullptr, nullptr, nullptr, nullptr, S, nullptr, lsum);

  // O = (P' @ V) / rowsum   (vt is [512][1024] per batch)
  // batch-mode: 4 batches per XCD, 8 tiles each
  gemm8p<4><<<256, 512, 0, stream>>>(
      S, vt, 2, 8, 512, 1024, 1, 0, 4, 1024 * 1024, 512 * 1024, 1024 * 512,
      nullptr, nullptr, nullptr, nullptr, nullptr, zO, nullptr, lsum);

  // out = O @ w_out^T + b_out + x
  // row-mode: XCD slab of 16 m-blocks, 2 panels cycle fastest
  gemm8p<2><<<256, 512, 0, stream>>>(
      zO, woutT, 2, 256, 512, 512, 0, 16, 0, 0, 0, 0, b_out, x,
      nullptr, nullptr, nullptr, nullptr, out, nullptr);
}